// Round 4
// baseline (1184.281 us; speedup 1.0000x reference)
//
#include <hip/hip_runtime.h>
#include <math.h>

#define N_NODES 50000
#define N_EDGES 500000
#define NLAYERS 6
#define NEG_SLOPE 0.2f
#define LN_EPS 1e-5f
#define SCAN_B 1024
#define NSCAN_BLOCKS ((N_NODES + SCAN_B - 1) / SCAN_B)  // 49

__device__ __forceinline__ int wave_incl_scan(int v, int lane) {
#pragma unroll
    for (int offs = 1; offs < 64; offs <<= 1) {
        int t = __shfl_up(v, offs, 64);
        if (lane >= offs) v += t;
    }
    return v;
}

// ---------------- CSR build ----------------
__global__ void count_deg(const int* __restrict__ dst, int* __restrict__ deg) {
    int i = blockIdx.x * blockDim.x + threadIdx.x;
    if (i < N_EDGES) atomicAdd(&deg[dst[i]], 1);
}

__global__ void scan1(const int* __restrict__ deg, int* __restrict__ row_ptr,
                      int* __restrict__ bsum) {
    int i = blockIdx.x * SCAN_B + threadIdx.x;
    int lane = threadIdx.x & 63, wv = threadIdx.x >> 6;
    int v = (i < N_NODES) ? deg[i] : 0;
    int incl = wave_incl_scan(v, lane);
    __shared__ int wtot[16];
    if (lane == 63) wtot[wv] = incl;
    __syncthreads();
    if (wv == 0) {
        int wval = (lane < 16) ? wtot[lane] : 0;
        int ws = wave_incl_scan(wval, lane);
        if (lane < 16) wtot[lane] = ws - wval;
    }
    __syncthreads();
    int excl = incl - v + wtot[wv];
    if (i < N_NODES) row_ptr[i] = excl;
    if (threadIdx.x == SCAN_B - 1) bsum[blockIdx.x] = excl + v;
}

__global__ void scan2(const int* __restrict__ bsum, int* __restrict__ boffs) {
    int lane = threadIdx.x;
    int v = (lane < NSCAN_BLOCKS) ? bsum[lane] : 0;
    int incl = wave_incl_scan(v, lane);
    if (lane < NSCAN_BLOCKS) boffs[lane] = incl - v;
}

__global__ void scan3(int* __restrict__ row_ptr, const int* __restrict__ boffs,
                      int* __restrict__ pos) {
    int i = blockIdx.x * SCAN_B + threadIdx.x;
    if (i < N_NODES) {
        int r = row_ptr[i] + boffs[blockIdx.x];
        row_ptr[i] = r;
        pos[i] = r;
    }
    if (i == 0) row_ptr[N_NODES] = N_EDGES;
}

__global__ void scatter_edges(const int* __restrict__ dst, const int* __restrict__ src,
                              int* __restrict__ pos, int* __restrict__ srcs) {
    int i = blockIdx.x * blockDim.x + threadIdx.x;
    if (i < N_EDGES) {
        int p = atomicAdd(&pos[dst[i]], 1);
        srcs[p] = src[i];
    }
}

// ---------------- [n,64] @ [64,64] + b, W in registers, x broadcast via readlane ----------
__global__ void mm64_reg(const float* __restrict__ X, const float* __restrict__ W,
                         const float* __restrict__ b, float* __restrict__ Y, int n) {
    int lane = threadIdx.x & 63, wv = threadIdx.x >> 6;
    int r0 = blockIdx.x * 32 + wv * 8;
    float wreg[64];
#pragma unroll
    for (int k = 0; k < 64; ++k) wreg[k] = W[(size_t)k * 64 + lane];
    float xr[8];
#pragma unroll
    for (int r = 0; r < 8; ++r) {
        int row = r0 + r;
        xr[r] = (row < n) ? X[(size_t)row * 64 + lane] : 0.f;
    }
    float acc[8];
    float bv = b[lane];
#pragma unroll
    for (int r = 0; r < 8; ++r) acc[r] = bv;
#pragma unroll
    for (int k = 0; k < 64; ++k) {
        float wk = wreg[k];
#pragma unroll
        for (int r = 0; r < 8; ++r) {
            float xb = __int_as_float(__builtin_amdgcn_readlane(__float_as_int(xr[r]), k));
            acc[r] = fmaf(xb, wk, acc[r]);
        }
    }
#pragma unroll
    for (int r = 0; r < 8; ++r) {
        int row = r0 + r;
        if (row < n) Y[(size_t)row * 64 + lane] = acc[r];
    }
}

// ---------------- dual dense: fs = h@Ws+bs, fd = h@Wd+bd, zero-DS inner loop ------------
__global__ void mm64_dual(const float* __restrict__ X, const float* __restrict__ Wsg,
                          const float* __restrict__ bsg, const float* __restrict__ Wdg,
                          const float* __restrict__ bdg, float* __restrict__ FS,
                          float* __restrict__ FD, int n) {
    int lane = threadIdx.x & 63, wv = threadIdx.x >> 6;
    int r0 = blockIdx.x * 32 + wv * 8;
    float ws[64], wd[64];
#pragma unroll
    for (int k = 0; k < 64; ++k) ws[k] = Wsg[(size_t)k * 64 + lane];
#pragma unroll
    for (int k = 0; k < 64; ++k) wd[k] = Wdg[(size_t)k * 64 + lane];
    float xr[8];
#pragma unroll
    for (int r = 0; r < 8; ++r) {
        int row = r0 + r;
        xr[r] = (row < n) ? X[(size_t)row * 64 + lane] : 0.f;
    }
    float as[8], ad[8];
    float bsv = bsg[lane], bdv = bdg[lane];
#pragma unroll
    for (int r = 0; r < 8; ++r) {
        as[r] = bsv;
        ad[r] = bdv;
    }
#pragma unroll
    for (int k = 0; k < 64; ++k) {
        float wsk = ws[k], wdk = wd[k];
#pragma unroll
        for (int r = 0; r < 8; ++r) {
            float xb = __int_as_float(__builtin_amdgcn_readlane(__float_as_int(xr[r]), k));
            as[r] = fmaf(xb, wsk, as[r]);
            ad[r] = fmaf(xb, wdk, ad[r]);
        }
    }
#pragma unroll
    for (int r = 0; r < 8; ++r) {
        int row = r0 + r;
        if (row < n) {
            FS[(size_t)row * 64 + lane] = as[r];
            FD[(size_t)row * 64 + lane] = ad[r];
        }
    }
}

// ---------------- fused per-node, quarter-wave: 4 edges in flight per wave --------------
// lane = (q<<4)|ql ; quarter q owns edge stream beg+4t+q ; lane ql holds features 4ql..4ql+3
#define WPB 4  // waves per block
#define NPW 4  // nodes per wave (sequential)
__global__ void node_fused_kernel(const float* __restrict__ fs, const float* __restrict__ fd,
                                  const int* __restrict__ row_ptr, const int* __restrict__ srcs,
                                  const float* __restrict__ attn, const float* __restrict__ gamma,
                                  const float* __restrict__ beta, float* __restrict__ h) {
    int lane = threadIdx.x & 63;
    int wv = threadIdx.x >> 6;
    int q = lane >> 4;
    int ql = lane & 15;
    int f0 = ql << 2;
    float4 a4 = *(const float4*)&attn[f0];
    float4 g4 = *(const float4*)&gamma[f0];
    float4 b4 = *(const float4*)&beta[f0];
    int base = blockIdx.x * (WPB * NPW) + wv * NPW;
    for (int p = 0; p < NPW; ++p) {
        int n = base + p;
        if (n >= N_NODES) break;
        int beg = row_ptr[n], end = row_ptr[n + 1];
        float4 fd4 = *(const float4*)&fd[(size_t)n * 64 + f0];
        float4 hv4 = make_float4(0.f, 0.f, 0.f, 0.f);
        if (q == 0) hv4 = *(const float4*)&h[(size_t)n * 64 + f0];  // early, latency hidden
        float m = -INFINITY, d = 0.f;
        float4 acc = make_float4(0.f, 0.f, 0.f, 0.f);
        int e = beg + q;
        float4 row = make_float4(0.f, 0.f, 0.f, 0.f);
        if (e < end) row = *(const float4*)&fs[(size_t)srcs[e] * 64 + f0];
        int nt = (end - beg + 3) >> 2;
        for (int t = 0; t < nt; ++t) {
            bool valid = e < end;
            float4 cur = row;
            int en = e + 4;
            row = make_float4(0.f, 0.f, 0.f, 0.f);
            if (en < end) row = *(const float4*)&fs[(size_t)srcs[en] * 64 + f0];  // prefetch
            float vx = cur.x + fd4.x, vy = cur.y + fd4.y;
            float vz = cur.z + fd4.z, vw = cur.w + fd4.w;
            vx = fmaxf(vx, NEG_SLOPE * vx);
            vy = fmaxf(vy, NEG_SLOPE * vy);
            vz = fmaxf(vz, NEG_SLOPE * vz);
            vw = fmaxf(vw, NEG_SLOPE * vw);
            float sp = fmaf(a4.x, vx, fmaf(a4.y, vy, fmaf(a4.z, vz, a4.w * vw)));
            sp += __shfl_xor(sp, 1, 64);
            sp += __shfl_xor(sp, 2, 64);
            sp += __shfl_xor(sp, 4, 64);
            sp += __shfl_xor(sp, 8, 64);
            if (valid) {
                if (sp > m) {
                    float sc = __expf(m - sp);
                    d *= sc;
                    acc.x *= sc;
                    acc.y *= sc;
                    acc.z *= sc;
                    acc.w *= sc;
                    m = sp;
                }
                float w = __expf(sp - m);
                d += w;
                acc.x = fmaf(w, cur.x, acc.x);
                acc.y = fmaf(w, cur.y, acc.y);
                acc.z = fmaf(w, cur.z, acc.z);
                acc.w = fmaf(w, cur.w, acc.w);
            }
            e = en;
        }
        // merge the 4 per-quarter online-softmax states
        float mo = fmaxf(m, __shfl_xor(m, 16, 64));
        mo = fmaxf(mo, __shfl_xor(mo, 32, 64));
        float scale = (m == -INFINITY) ? 0.f : __expf(m - mo);
        d *= scale;
        d += __shfl_xor(d, 16, 64);
        d += __shfl_xor(d, 32, 64);
        acc.x *= scale;
        acc.y *= scale;
        acc.z *= scale;
        acc.w *= scale;
        acc.x += __shfl_xor(acc.x, 16, 64);
        acc.y += __shfl_xor(acc.y, 16, 64);
        acc.z += __shfl_xor(acc.z, 16, 64);
        acc.w += __shfl_xor(acc.w, 16, 64);
        acc.x += __shfl_xor(acc.x, 32, 64);
        acc.y += __shfl_xor(acc.y, 32, 64);
        acc.z += __shfl_xor(acc.z, 32, 64);
        acc.w += __shfl_xor(acc.w, 32, 64);
        float inv = (d > 0.f) ? 1.f / d : 0.f;
        acc.x *= inv;
        acc.y *= inv;
        acc.z *= inv;
        acc.w *= inv;
        // layernorm over 64 features (16 lanes x 4 each; quarters hold identical copies)
        float s = acc.x + acc.y + acc.z + acc.w;
        s += __shfl_xor(s, 1, 64);
        s += __shfl_xor(s, 2, 64);
        s += __shfl_xor(s, 4, 64);
        s += __shfl_xor(s, 8, 64);
        float mean = s * 0.015625f;
        float dx = acc.x - mean, dy = acc.y - mean, dz = acc.z - mean, dw = acc.w - mean;
        float vs = fmaf(dx, dx, fmaf(dy, dy, fmaf(dz, dz, dw * dw)));
        vs += __shfl_xor(vs, 1, 64);
        vs += __shfl_xor(vs, 2, 64);
        vs += __shfl_xor(vs, 4, 64);
        vs += __shfl_xor(vs, 8, 64);
        float rstd = rsqrtf(vs * 0.015625f + LN_EPS);
        float tx = fmaf(dx * rstd, g4.x, b4.x);
        float ty = fmaf(dy * rstd, g4.y, b4.y);
        float tz = fmaf(dz * rstd, g4.z, b4.z);
        float tw = fmaf(dw * rstd, g4.w, b4.w);
        const float IS2 = 0.70710678118654752f;
        float gx = 0.5f * tx * (1.f + erff(tx * IS2));
        float gy = 0.5f * ty * (1.f + erff(ty * IS2));
        float gz = 0.5f * tz * (1.f + erff(tz * IS2));
        float gw = 0.5f * tw * (1.f + erff(tw * IS2));
        if (q == 0) {
            hv4.x += gx;
            hv4.y += gy;
            hv4.z += gz;
            hv4.w += gw;
            *(float4*)&h[(size_t)n * 64 + f0] = hv4;
        }
    }
}

// ---------------- output projection [n,64] @ [64,8] + b ----------------
__global__ void out_proj_kernel(const float* __restrict__ h, const float* __restrict__ W,
                                const float* __restrict__ b, float* __restrict__ out) {
    __shared__ float Ws[64 * 8];
    __shared__ float bs[8];
    __shared__ float Hs[32][65];
    int t = threadIdx.x;
    for (int i = t; i < 512; i += 256) Ws[i] = W[i];
    if (t < 8) bs[t] = b[t];
    int n0 = blockIdx.x * 32;
    for (int i = t; i < 32 * 64; i += 256) {
        int r = i >> 6, c = i & 63;
        int n = n0 + r;
        Hs[r][c] = (n < N_NODES) ? h[(size_t)n * 64 + c] : 0.f;
    }
    __syncthreads();
    int nl = t >> 3, o = t & 7;
    int n = n0 + nl;
    if (n >= N_NODES) return;
    float acc = bs[o];
#pragma unroll
    for (int k = 0; k < 64; ++k) acc = fmaf(Hs[nl][k], Ws[k * 8 + o], acc);
    out[(size_t)n * 8 + o] = acc;
}

extern "C" void kernel_launch(void* const* d_in, const int* in_sizes, int n_in,
                              void* d_out, int out_size, void* d_ws, size_t ws_size,
                              hipStream_t stream) {
    const float* nodes = (const float*)d_in[0];
    const int* src = (const int*)d_in[1];
    const int* dst = (const int*)d_in[2];
    const float* w_in = (const float*)d_in[3];
    const float* b_in = (const float*)d_in[4];
    const float* w_src = (const float*)d_in[5];
    const float* b_src = (const float*)d_in[6];
    const float* w_dst = (const float*)d_in[7];
    const float* b_dst = (const float*)d_in[8];
    const float* attn = (const float*)d_in[9];
    const float* gamma = (const float*)d_in[10];
    const float* beta = (const float*)d_in[11];
    const float* w_out = (const float*)d_in[12];
    const float* b_out = (const float*)d_in[13];
    float* out = (float*)d_out;

    char* ws = (char*)d_ws;
    size_t off = 0;
    auto alloc = [&](size_t bytes) {
        void* p = ws + off;
        off += (bytes + 255) & ~(size_t)255;
        return p;
    };
    float* h = (float*)alloc((size_t)N_NODES * 64 * 4);
    float* fs = (float*)alloc((size_t)N_NODES * 64 * 4);
    float* fd = (float*)alloc((size_t)N_NODES * 64 * 4);
    int* deg = (int*)alloc((size_t)N_NODES * 4);
    int* row_ptr = (int*)alloc((size_t)(N_NODES + 1) * 4);
    int* pos = (int*)alloc((size_t)N_NODES * 4);
    int* srcs = (int*)alloc((size_t)N_EDGES * 4);
    int* bsum = (int*)alloc((size_t)NSCAN_BLOCKS * 4);
    int* boffs = (int*)alloc((size_t)NSCAN_BLOCKS * 4);

    // CSR by dst (graph static across layers); srcs[] = src id in CSR slot order
    hipMemsetAsync(deg, 0, (size_t)N_NODES * 4, stream);
    count_deg<<<(N_EDGES + 255) / 256, 256, 0, stream>>>(dst, deg);
    scan1<<<NSCAN_BLOCKS, SCAN_B, 0, stream>>>(deg, row_ptr, bsum);
    scan2<<<1, 64, 0, stream>>>(bsum, boffs);
    scan3<<<NSCAN_BLOCKS, SCAN_B, 0, stream>>>(row_ptr, boffs, pos);
    scatter_edges<<<(N_EDGES + 255) / 256, 256, 0, stream>>>(dst, src, pos, srcs);

    // input projection
    mm64_reg<<<(N_NODES + 31) / 32, 256, 0, stream>>>(nodes, w_in, b_in, h, N_NODES);

    for (int l = 0; l < NLAYERS; ++l) {
        mm64_dual<<<(N_NODES + 31) / 32, 256, 0, stream>>>(
            h, w_src + (size_t)l * 4096, b_src + (size_t)l * 64, w_dst + (size_t)l * 4096,
            b_dst + (size_t)l * 64, fs, fd, N_NODES);
        node_fused_kernel<<<(N_NODES + WPB * NPW - 1) / (WPB * NPW), 256, 0, stream>>>(
            fs, fd, row_ptr, srcs, attn + (size_t)l * 64, gamma + (size_t)l * 64,
            beta + (size_t)l * 64, h);
    }

    out_proj_kernel<<<(N_NODES + 31) / 32, 256, 0, stream>>>(h, w_out, b_out, out);
}

// Round 5
// 494.060 us; speedup vs baseline: 2.3970x; 2.3970x over previous
//
#include <hip/hip_runtime.h>
#include <math.h>

#define N_NODES 50000
#define N_EDGES 500000
#define NLAYERS 6
#define NEG_SLOPE 0.2f
#define LN_EPS 1e-5f
#define SCAN_B 1024
#define NSCAN_BLOCKS ((N_NODES + SCAN_B - 1) / SCAN_B)  // 49
#define MM_ROWS 32

__device__ __forceinline__ int wave_incl_scan(int v, int lane) {
#pragma unroll
    for (int offs = 1; offs < 64; offs <<= 1) {
        int t = __shfl_up(v, offs, 64);
        if (lane >= offs) v += t;
    }
    return v;
}

// ---------------- CSR build ----------------
__global__ void count_deg(const int* __restrict__ dst, int* __restrict__ deg) {
    int i = blockIdx.x * blockDim.x + threadIdx.x;
    if (i < N_EDGES) atomicAdd(&deg[dst[i]], 1);
}

__global__ void scan1(const int* __restrict__ deg, int* __restrict__ row_ptr,
                      int* __restrict__ bsum) {
    int i = blockIdx.x * SCAN_B + threadIdx.x;
    int lane = threadIdx.x & 63, wv = threadIdx.x >> 6;
    int v = (i < N_NODES) ? deg[i] : 0;
    int incl = wave_incl_scan(v, lane);
    __shared__ int wtot[16];
    if (lane == 63) wtot[wv] = incl;
    __syncthreads();
    if (wv == 0) {
        int wval = (lane < 16) ? wtot[lane] : 0;
        int ws = wave_incl_scan(wval, lane);
        if (lane < 16) wtot[lane] = ws - wval;
    }
    __syncthreads();
    int excl = incl - v + wtot[wv];
    if (i < N_NODES) row_ptr[i] = excl;
    if (threadIdx.x == SCAN_B - 1) bsum[blockIdx.x] = excl + v;
}

__global__ void scan2(const int* __restrict__ bsum, int* __restrict__ boffs) {
    int lane = threadIdx.x;
    int v = (lane < NSCAN_BLOCKS) ? bsum[lane] : 0;
    int incl = wave_incl_scan(v, lane);
    if (lane < NSCAN_BLOCKS) boffs[lane] = incl - v;
}

__global__ void scan3(int* __restrict__ row_ptr, const int* __restrict__ boffs,
                      int* __restrict__ pos) {
    int i = blockIdx.x * SCAN_B + threadIdx.x;
    if (i < N_NODES) {
        int r = row_ptr[i] + boffs[blockIdx.x];
        row_ptr[i] = r;
        pos[i] = r;
    }
    if (i == 0) row_ptr[N_NODES] = N_EDGES;
}

__global__ void scatter_edges(const int* __restrict__ dst, const int* __restrict__ src,
                              int* __restrict__ pos, int* __restrict__ srcs) {
    int i = blockIdx.x * blockDim.x + threadIdx.x;
    if (i < N_EDGES) {
        int p = atomicAdd(&pos[dst[i]], 1);
        srcs[p] = src[i];
    }
}

// ---------------- dense [n,64] @ [64,64] + b (input projection), LDS W ----------------
__global__ void mm64_kernel(const float* __restrict__ X, const float* __restrict__ W,
                            const float* __restrict__ b, float* __restrict__ Y, int n) {
    __shared__ float Ws[64][64];
    __shared__ float bs[64];
    int t = threadIdx.x;
    for (int i = t; i < 64 * 64; i += 256) Ws[i >> 6][i & 63] = W[i];
    if (t < 64) bs[t] = b[t];
    __syncthreads();
    int lane = t & 63;
    int rg = t >> 6;
    int base = blockIdx.x * MM_ROWS;
    for (int r = rg; r < MM_ROWS; r += 4) {
        int row = base + r;
        if (row >= n) break;
        const float* x = X + (size_t)row * 64;
        float acc = bs[lane];
#pragma unroll
        for (int k = 0; k < 64; ++k) acc = fmaf(x[k], Ws[k][lane], acc);
        Y[(size_t)row * 64 + lane] = acc;
    }
}

// ---------------- dual dense: fs = h@Ws+bs, fd = h@Wd+bd, LDS W (known-good) ------------
#define DROWS 32
__global__ void mm64_dual(const float* __restrict__ X, const float* __restrict__ Wsg,
                          const float* __restrict__ bsg, const float* __restrict__ Wdg,
                          const float* __restrict__ bdg, float* __restrict__ FS,
                          float* __restrict__ FD, int n) {
    __shared__ float Ws[64][64];
    __shared__ float Wd[64][64];
    __shared__ float xs[4][8][64];
    __shared__ float bsh[64], bdh[64];
    int t = threadIdx.x;
    for (int i = t; i < 4096; i += 256) {
        Ws[i >> 6][i & 63] = Wsg[i];
        Wd[i >> 6][i & 63] = Wdg[i];
    }
    if (t < 64) {
        bsh[t] = bsg[t];
        bdh[t] = bdg[t];
    }
    int lane = t & 63, wv = t >> 6;
    int r0 = blockIdx.x * DROWS + wv * 8;
#pragma unroll
    for (int r = 0; r < 8; ++r) {
        int row = r0 + r;
        xs[wv][r][lane] = (row < n) ? X[(size_t)row * 64 + lane] : 0.f;
    }
    __syncthreads();
    float as[8], ad[8];
    float bsv = bsh[lane], bdv = bdh[lane];
#pragma unroll
    for (int r = 0; r < 8; ++r) {
        as[r] = bsv;
        ad[r] = bdv;
    }
    for (int k4 = 0; k4 < 16; ++k4) {
        int k = k4 * 4;
        float ws0 = Ws[k + 0][lane], ws1 = Ws[k + 1][lane];
        float ws2 = Ws[k + 2][lane], ws3 = Ws[k + 3][lane];
        float wd0 = Wd[k + 0][lane], wd1 = Wd[k + 1][lane];
        float wd2 = Wd[k + 2][lane], wd3 = Wd[k + 3][lane];
#pragma unroll
        for (int r = 0; r < 8; ++r) {
            float4 xv = *(const float4*)&xs[wv][r][k];
            as[r] = fmaf(xv.x, ws0, as[r]);
            as[r] = fmaf(xv.y, ws1, as[r]);
            as[r] = fmaf(xv.z, ws2, as[r]);
            as[r] = fmaf(xv.w, ws3, as[r]);
            ad[r] = fmaf(xv.x, wd0, ad[r]);
            ad[r] = fmaf(xv.y, wd1, ad[r]);
            ad[r] = fmaf(xv.z, wd2, ad[r]);
            ad[r] = fmaf(xv.w, wd3, ad[r]);
        }
    }
#pragma unroll
    for (int r = 0; r < 8; ++r) {
        int row = r0 + r;
        if (row < n) {
            FS[(size_t)row * 64 + lane] = as[r];
            FD[(size_t)row * 64 + lane] = ad[r];
        }
    }
}

// ---------------- fused per-node, quarter-wave, one node per wave ----------------------
// lane = (q<<4)|ql ; quarter q owns edge stream 4t+q ; lane ql holds features 4ql..4ql+3
// srcs for the whole segment pre-loaded (64-wide coalesced) and broadcast via shfl;
// fs rows prefetched 2 iterations deep.
#define WPB 4  // waves per block, 1 node per wave
__global__ void node_fused_kernel(const float* __restrict__ fs, const float* __restrict__ fd,
                                  const int* __restrict__ row_ptr, const int* __restrict__ srcs,
                                  const float* __restrict__ attn, const float* __restrict__ gamma,
                                  const float* __restrict__ beta, float* __restrict__ h) {
    int lane = threadIdx.x & 63;
    int wv = threadIdx.x >> 6;
    int q = lane >> 4;
    int ql = lane & 15;
    int f0 = ql << 2;
    int n = blockIdx.x * WPB + wv;
    if (n >= N_NODES) return;
    float4 a4 = *(const float4*)&attn[f0];
    float4 g4 = *(const float4*)&gamma[f0];
    float4 b4 = *(const float4*)&beta[f0];
    int beg = row_ptr[n], end = row_ptr[n + 1];
    int deg = end - beg;
    float4 fd4 = *(const float4*)&fd[(size_t)n * 64 + f0];
    float4 hv4 = make_float4(0.f, 0.f, 0.f, 0.f);
    if (q == 0) hv4 = *(const float4*)&h[(size_t)n * 64 + f0];  // early issue
    float m = -INFINITY, d = 0.f;
    float4 acc = make_float4(0.f, 0.f, 0.f, 0.f);
    for (int c0 = 0; c0 < deg; c0 += 64) {
        int cl = min(64, deg - c0);  // chunk length (deg>64 is rare; avg deg = 10)
        int sv = (lane < cl) ? srcs[beg + c0 + lane] : 0;
        int nt = (cl + 3) >> 2;
        // prologue: prefetch iterations t=0 and t=1
        int e0 = q;
        int sid0 = __shfl(sv, e0, 64);
        float4 rowA = make_float4(0.f, 0.f, 0.f, 0.f);
        if (e0 < cl) rowA = *(const float4*)&fs[(size_t)sid0 * 64 + f0];
        int e1 = 4 + q;
        int sid1 = __shfl(sv, e1 & 63, 64);
        float4 rowB = make_float4(0.f, 0.f, 0.f, 0.f);
        if (e1 < cl) rowB = *(const float4*)&fs[(size_t)sid1 * 64 + f0];
        for (int t = 0; t < nt; ++t) {
            int eoff = 4 * t + q;
            bool valid = eoff < cl;
            float4 cur = rowA;
            rowA = rowB;
            int e2 = 4 * (t + 2) + q;
            int sid2 = __shfl(sv, e2 & 63, 64);
            rowB = make_float4(0.f, 0.f, 0.f, 0.f);
            if (e2 < cl) rowB = *(const float4*)&fs[(size_t)sid2 * 64 + f0];
            float vx = cur.x + fd4.x, vy = cur.y + fd4.y;
            float vz = cur.z + fd4.z, vw = cur.w + fd4.w;
            vx = fmaxf(vx, NEG_SLOPE * vx);
            vy = fmaxf(vy, NEG_SLOPE * vy);
            vz = fmaxf(vz, NEG_SLOPE * vz);
            vw = fmaxf(vw, NEG_SLOPE * vw);
            float sp = fmaf(a4.x, vx, fmaf(a4.y, vy, fmaf(a4.z, vz, a4.w * vw)));
            sp += __shfl_xor(sp, 1, 64);
            sp += __shfl_xor(sp, 2, 64);
            sp += __shfl_xor(sp, 4, 64);
            sp += __shfl_xor(sp, 8, 64);
            if (valid) {
                if (sp > m) {
                    float sc = __expf(m - sp);
                    d *= sc;
                    acc.x *= sc;
                    acc.y *= sc;
                    acc.z *= sc;
                    acc.w *= sc;
                    m = sp;
                }
                float w = __expf(sp - m);
                d += w;
                acc.x = fmaf(w, cur.x, acc.x);
                acc.y = fmaf(w, cur.y, acc.y);
                acc.z = fmaf(w, cur.z, acc.z);
                acc.w = fmaf(w, cur.w, acc.w);
            }
        }
    }
    // merge the 4 per-quarter online-softmax states
    float mo = fmaxf(m, __shfl_xor(m, 16, 64));
    mo = fmaxf(mo, __shfl_xor(mo, 32, 64));
    float scale = (m == -INFINITY) ? 0.f : __expf(m - mo);
    d *= scale;
    d += __shfl_xor(d, 16, 64);
    d += __shfl_xor(d, 32, 64);
    acc.x *= scale;
    acc.y *= scale;
    acc.z *= scale;
    acc.w *= scale;
    acc.x += __shfl_xor(acc.x, 16, 64);
    acc.y += __shfl_xor(acc.y, 16, 64);
    acc.z += __shfl_xor(acc.z, 16, 64);
    acc.w += __shfl_xor(acc.w, 16, 64);
    acc.x += __shfl_xor(acc.x, 32, 64);
    acc.y += __shfl_xor(acc.y, 32, 64);
    acc.z += __shfl_xor(acc.z, 32, 64);
    acc.w += __shfl_xor(acc.w, 32, 64);
    float inv = (d > 0.f) ? 1.f / d : 0.f;
    acc.x *= inv;
    acc.y *= inv;
    acc.z *= inv;
    acc.w *= inv;
    // layernorm over 64 features (16 lanes x 4 each; quarters hold identical copies)
    float s = acc.x + acc.y + acc.z + acc.w;
    s += __shfl_xor(s, 1, 64);
    s += __shfl_xor(s, 2, 64);
    s += __shfl_xor(s, 4, 64);
    s += __shfl_xor(s, 8, 64);
    float mean = s * 0.015625f;
    float dx = acc.x - mean, dy = acc.y - mean, dz = acc.z - mean, dw = acc.w - mean;
    float vs = fmaf(dx, dx, fmaf(dy, dy, fmaf(dz, dz, dw * dw)));
    vs += __shfl_xor(vs, 1, 64);
    vs += __shfl_xor(vs, 2, 64);
    vs += __shfl_xor(vs, 4, 64);
    vs += __shfl_xor(vs, 8, 64);
    float rstd = rsqrtf(vs * 0.015625f + LN_EPS);
    float tx = fmaf(dx * rstd, g4.x, b4.x);
    float ty = fmaf(dy * rstd, g4.y, b4.y);
    float tz = fmaf(dz * rstd, g4.z, b4.z);
    float tw = fmaf(dw * rstd, g4.w, b4.w);
    const float IS2 = 0.70710678118654752f;
    float gx = 0.5f * tx * (1.f + erff(tx * IS2));
    float gy = 0.5f * ty * (1.f + erff(ty * IS2));
    float gz = 0.5f * tz * (1.f + erff(tz * IS2));
    float gw = 0.5f * tw * (1.f + erff(tw * IS2));
    if (q == 0) {
        hv4.x += gx;
        hv4.y += gy;
        hv4.z += gz;
        hv4.w += gw;
        *(float4*)&h[(size_t)n * 64 + f0] = hv4;
    }
}

// ---------------- output projection [n,64] @ [64,8] + b ----------------
__global__ void out_proj_kernel(const float* __restrict__ h, const float* __restrict__ W,
                                const float* __restrict__ b, float* __restrict__ out) {
    __shared__ float Ws[64 * 8];
    __shared__ float bs[8];
    __shared__ float Hs[32][65];
    int t = threadIdx.x;
    for (int i = t; i < 512; i += 256) Ws[i] = W[i];
    if (t < 8) bs[t] = b[t];
    int n0 = blockIdx.x * 32;
    for (int i = t; i < 32 * 64; i += 256) {
        int r = i >> 6, c = i & 63;
        int n = n0 + r;
        Hs[r][c] = (n < N_NODES) ? h[(size_t)n * 64 + c] : 0.f;
    }
    __syncthreads();
    int nl = t >> 3, o = t & 7;
    int n = n0 + nl;
    if (n >= N_NODES) return;
    float acc = bs[o];
#pragma unroll
    for (int k = 0; k < 64; ++k) acc = fmaf(Hs[nl][k], Ws[k * 8 + o], acc);
    out[(size_t)n * 8 + o] = acc;
}

extern "C" void kernel_launch(void* const* d_in, const int* in_sizes, int n_in,
                              void* d_out, int out_size, void* d_ws, size_t ws_size,
                              hipStream_t stream) {
    const float* nodes = (const float*)d_in[0];
    const int* src = (const int*)d_in[1];
    const int* dst = (const int*)d_in[2];
    const float* w_in = (const float*)d_in[3];
    const float* b_in = (const float*)d_in[4];
    const float* w_src = (const float*)d_in[5];
    const float* b_src = (const float*)d_in[6];
    const float* w_dst = (const float*)d_in[7];
    const float* b_dst = (const float*)d_in[8];
    const float* attn = (const float*)d_in[9];
    const float* gamma = (const float*)d_in[10];
    const float* beta = (const float*)d_in[11];
    const float* w_out = (const float*)d_in[12];
    const float* b_out = (const float*)d_in[13];
    float* out = (float*)d_out;

    char* ws = (char*)d_ws;
    size_t off = 0;
    auto alloc = [&](size_t bytes) {
        void* p = ws + off;
        off += (bytes + 255) & ~(size_t)255;
        return p;
    };
    float* h = (float*)alloc((size_t)N_NODES * 64 * 4);
    float* fs = (float*)alloc((size_t)N_NODES * 64 * 4);
    float* fd = (float*)alloc((size_t)N_NODES * 64 * 4);
    int* deg = (int*)alloc((size_t)N_NODES * 4);
    int* row_ptr = (int*)alloc((size_t)(N_NODES + 1) * 4);
    int* pos = (int*)alloc((size_t)N_NODES * 4);
    int* srcs = (int*)alloc((size_t)N_EDGES * 4);
    int* bsum = (int*)alloc((size_t)NSCAN_BLOCKS * 4);
    int* boffs = (int*)alloc((size_t)NSCAN_BLOCKS * 4);

    // CSR by dst (graph static across layers); srcs[] = src id in CSR slot order
    hipMemsetAsync(deg, 0, (size_t)N_NODES * 4, stream);
    count_deg<<<(N_EDGES + 255) / 256, 256, 0, stream>>>(dst, deg);
    scan1<<<NSCAN_BLOCKS, SCAN_B, 0, stream>>>(deg, row_ptr, bsum);
    scan2<<<1, 64, 0, stream>>>(bsum, boffs);
    scan3<<<NSCAN_BLOCKS, SCAN_B, 0, stream>>>(row_ptr, boffs, pos);
    scatter_edges<<<(N_EDGES + 255) / 256, 256, 0, stream>>>(dst, src, pos, srcs);

    // input projection
    mm64_kernel<<<(N_NODES + MM_ROWS - 1) / MM_ROWS, 256, 0, stream>>>(nodes, w_in, b_in, h,
                                                                       N_NODES);

    for (int l = 0; l < NLAYERS; ++l) {
        mm64_dual<<<(N_NODES + DROWS - 1) / DROWS, 256, 0, stream>>>(
            h, w_src + (size_t)l * 4096, b_src + (size_t)l * 64, w_dst + (size_t)l * 4096,
            b_dst + (size_t)l * 64, fs, fd, N_NODES);
        node_fused_kernel<<<(N_NODES + WPB - 1) / WPB, 256, 0, stream>>>(
            fs, fd, row_ptr, srcs, attn + (size_t)l * 64, gamma + (size_t)l * 64,
            beta + (size_t)l * 64, h);
    }

    out_proj_kernel<<<(N_NODES + 31) / 32, 256, 0, stream>>>(h, w_out, b_out, out);
}